// Round 7
// baseline (3890.065 us; speedup 1.0000x reference)
//
#include <hip/hip_runtime.h>
#include <hip/hip_cooperative_groups.h>

namespace cg = cooperative_groups;

#define N_NODES 100000
#define N_EDGES 1600000
#define D_IN    256
#define D_HID   64
#define D_OUT   32
#define NPROP   10

#define NBUCK 196          // bucket = row >> 9 (512 rows/bucket)
#define CHUNK 6080         // edges per bscatter block (LDS-limited)
#define NCHUNK ((N_EDGES + CHUNK - 1) / CHUNK)   // 264

typedef _Float16 half_t;
typedef _Float16 h8  __attribute__((ext_vector_type(8)));
typedef _Float16 h4  __attribute__((ext_vector_type(4)));
typedef float    f4v __attribute__((ext_vector_type(4)));

// ---------------- weight pack ----------------
__global__ __launch_bounds__(256) void pack_kernel(
    const float* __restrict__ W1, const float* __restrict__ W2,
    half_t* __restrict__ W1T, half_t* __restrict__ W2T)
{
  int t = blockIdx.x * 256 + threadIdx.x;
  if (t < 64 * 256) { int n = t >> 8, k = t & 255; W1T[t] = (half_t)W1[k * 64 + n]; }
  if (t < 32 * 64)  { int n = t >> 6, k = t & 63;  W2T[t] = (half_t)W2[k * 32 + n]; }
}

// ---------------- MLP head via MFMA (round-6, ~58 us) ----------------
#define HSTRIDE 72

__global__ __launch_bounds__(256, 2) void mlp_kernel(
    const float* __restrict__ F, const half_t* __restrict__ W1T,
    const float* __restrict__ b1, const half_t* __restrict__ W2T,
    const float* __restrict__ b2, half_t* __restrict__ x0h)
{
  __shared__ half_t h_lds[4 * 16 * HSTRIDE];   // per-wave 16x64 hidden (pad 72)
  __shared__ half_t out_lds[4 * 16 * 32];      // per-wave 16x32 output
  int t = threadIdx.x;
  int w = t >> 6, lane = t & 63;
  int m = lane & 15, q = lane >> 4;
  int gw = blockIdx.x * 4 + w;
  int node0 = gw * 16;
  if (node0 > N_NODES - 16) node0 = N_NODES - 16;  // tail waves duplicate last tile

  const float* ap = F + (size_t)(node0 + m) * D_IN + q * 8;
  float4 fr[16];
#pragma unroll
  for (int s = 0; s < 8; ++s) {
    fr[2 * s]     = *(const float4*)(ap + s * 32);
    fr[2 * s + 1] = *(const float4*)(ap + s * 32 + 4);
  }

  h8 af[8];
#pragma unroll
  for (int s = 0; s < 8; ++s) {
    float4 f0 = fr[2 * s], f1 = fr[2 * s + 1];
    h8 a;
    a[0] = (_Float16)f0.x; a[1] = (_Float16)f0.y;
    a[2] = (_Float16)f0.z; a[3] = (_Float16)f0.w;
    a[4] = (_Float16)f1.x; a[5] = (_Float16)f1.y;
    a[6] = (_Float16)f1.z; a[7] = (_Float16)f1.w;
    af[s] = a;
  }

  f4v acc[4];
#pragma unroll
  for (int i = 0; i < 4; ++i) acc[i] = (f4v){0.f, 0.f, 0.f, 0.f};
  const half_t* bp = W1T + (size_t)m * D_IN + q * 8;
#pragma unroll
  for (int s = 0; s < 8; ++s) {
    h8 b0 = *(const h8*)(bp + 0 * 16 * D_IN + s * 32);
    h8 b1v = *(const h8*)(bp + 1 * 16 * D_IN + s * 32);
    h8 b2v = *(const h8*)(bp + 2 * 16 * D_IN + s * 32);
    h8 b3v = *(const h8*)(bp + 3 * 16 * D_IN + s * 32);
    acc[0] = __builtin_amdgcn_mfma_f32_16x16x32_f16(af[s], b0, acc[0], 0, 0, 0);
    acc[1] = __builtin_amdgcn_mfma_f32_16x16x32_f16(af[s], b1v, acc[1], 0, 0, 0);
    acc[2] = __builtin_amdgcn_mfma_f32_16x16x32_f16(af[s], b2v, acc[2], 0, 0, 0);
    acc[3] = __builtin_amdgcn_mfma_f32_16x16x32_f16(af[s], b3v, acc[3], 0, 0, 0);
  }

  half_t* hw = h_lds + w * 16 * HSTRIDE;
#pragma unroll
  for (int ht = 0; ht < 4; ++ht) {
    float bb = b1[ht * 16 + m];
#pragma unroll
    for (int i = 0; i < 4; ++i) {
      float hv = fmaxf(acc[ht][i] + bb, 0.f);
      hw[(q * 4 + i) * HSTRIDE + ht * 16 + m] = (half_t)hv;
    }
  }
  __syncthreads();

  f4v o0 = {0.f, 0.f, 0.f, 0.f}, o1 = {0.f, 0.f, 0.f, 0.f};
#pragma unroll
  for (int s = 0; s < 2; ++s) {
    h8 a = *(const h8*)(hw + m * HSTRIDE + s * 32 + q * 8);
    h8 bb0 = *(const h8*)(W2T + (size_t)m * D_HID + s * 32 + q * 8);
    h8 bb1 = *(const h8*)(W2T + (size_t)(16 + m) * D_HID + s * 32 + q * 8);
    o0 = __builtin_amdgcn_mfma_f32_16x16x32_f16(a, bb0, o0, 0, 0, 0);
    o1 = __builtin_amdgcn_mfma_f32_16x16x32_f16(a, bb1, o1, 0, 0, 0);
  }
  half_t* ow = out_lds + w * 16 * 32;
  {
    float c0 = b2[m], c1 = b2[16 + m];
#pragma unroll
    for (int i = 0; i < 4; ++i) {
      ow[(q * 4 + i) * 32 + m]      = (half_t)(o0[i] + c0);
      ow[(q * 4 + i) * 32 + 16 + m] = (half_t)(o1[i] + c1);
    }
  }
  __syncthreads();

  {
    int nl = lane >> 2, qq = lane & 3;
    *(int4*)(x0h + (size_t)(node0 + nl) * D_OUT + qq * 8) =
        *(const int4*)(ow + nl * 32 + qq * 8);
  }
}

// ---------------- CSR build, two-pass bucketed sort (round-1 exact) ------
__global__ __launch_bounds__(256) void bhist_kernel(
    const int* __restrict__ row, int* __restrict__ bcnt)
{
  __shared__ int lb[NBUCK];
  int t = threadIdx.x;
  for (int i = t; i < NBUCK; i += 256) lb[i] = 0;
  __syncthreads();
  int stride = gridDim.x * 256;
  for (int e = blockIdx.x * 256 + t; e < N_EDGES; e += stride)
    atomicAdd(&lb[row[e] >> 9], 1);
  __syncthreads();
  for (int i = t; i < NBUCK; i += 256)
    if (lb[i]) atomicAdd(&bcnt[i], lb[i]);
}

__global__ __launch_bounds__(256) void bscan_kernel(
    const int* __restrict__ bcnt, int* __restrict__ bbase, int* __restrict__ pbase)
{
  __shared__ int l1[256], l2[256];
  int t = threadIdx.x;
  int a = (t < NBUCK) ? bcnt[t] : 0;
  int r = (t < NBUCK) ? (((a + 3) & ~3) + 3 * 512) : 0;
  l1[t] = a; l2[t] = r;
  __syncthreads();
  for (int off = 1; off < 256; off <<= 1) {
    int x1 = (t >= off) ? l1[t - off] : 0;
    int x2 = (t >= off) ? l2[t - off] : 0;
    __syncthreads();
    l1[t] += x1; l2[t] += x2;
    __syncthreads();
  }
  if (t < NBUCK) { bbase[t] = l1[t] - a; pbase[t] = l2[t] - r; }
  if (t == NBUCK - 1) { bbase[NBUCK] = l1[t]; pbase[NBUCK] = l2[t]; }
}

__global__ __launch_bounds__(256) void bscatter_kernel(
    const int* __restrict__ row, const int* __restrict__ col,
    const float* __restrict__ vals, int* __restrict__ bfill,
    const int* __restrict__ bbase, int2* __restrict__ ebuck)
{
  __shared__ int2 img[CHUNK];                 // 48,640 B
  __shared__ unsigned short sbk[CHUNK];       // 12,160 B
  __shared__ int cnt[NBUCK], base[NBUCK], gb[NBUCK], fil[NBUCK];
  __shared__ int ssc[256];
  int t = threadIdx.x;
  int e0 = blockIdx.x * CHUNK;
  int n = min(CHUNK, N_EDGES - e0);

  for (int i = t; i < NBUCK; i += 256) { cnt[i] = 0; fil[i] = 0; }
  __syncthreads();
  for (int i = t; i < n; i += 256) atomicAdd(&cnt[row[e0 + i] >> 9], 1);
  __syncthreads();
  int c = (t < NBUCK) ? cnt[t] : 0;
  ssc[t] = c;
  __syncthreads();
  for (int off = 1; off < 256; off <<= 1) {
    int add = (t >= off) ? ssc[t - off] : 0;
    __syncthreads();
    ssc[t] += add;
    __syncthreads();
  }
  if (t < NBUCK) {
    base[t] = ssc[t] - c;
    gb[t] = c ? atomicAdd(&bfill[t], c) : 0;
  }
  __syncthreads();
  for (int i = t; i < n; i += 256) {
    int r = row[e0 + i];
    int bk = r >> 9;
    int p = base[bk] + atomicAdd(&fil[bk], 1);
    img[p] = make_int2(col[e0 + i] | ((r & 511) << 17),
                       __float_as_int(vals[e0 + i]));
    sbk[p] = (unsigned short)bk;
  }
  __syncthreads();
  for (int i = t; i < n; i += 256) {
    int bk = sbk[i];
    ebuck[bbase[bk] + gb[bk] + (i - base[bk])] = img[i];
  }
}

__global__ __launch_bounds__(256) void bsort_kernel(
    const int* __restrict__ bbase, const int* __restrict__ pbase,
    const int2* __restrict__ ebuck, int2* __restrict__ epack,
    int* __restrict__ row_ptr)
{
  __shared__ int acnt[512], loff[513], lfill[512], ssc[256];
  int b = blockIdx.x, t = threadIdx.x;
  int r0 = b * 512;
  int nr = min(512, N_NODES - r0);
  int eb = bbase[b];
  int ne = bbase[b + 1] - eb;
  int pb = pbase[b];

  acnt[t] = 0; acnt[t + 256] = 0;
  lfill[t] = 0; lfill[t + 256] = 0;
  __syncthreads();
  for (int i = t; i < ne; i += 256)
    atomicAdd(&acnt[((unsigned)ebuck[eb + i].x) >> 17], 1);
  __syncthreads();
  int i0 = 2 * t, i1 = 2 * t + 1;
  int a0 = acnt[i0], a1 = acnt[i1];
  int p0 = (a0 + 3) & ~3, p1 = (a1 + 3) & ~3;
  int s = p0 + p1;
  ssc[t] = s;
  __syncthreads();
  for (int off = 1; off < 256; off <<= 1) {
    int add = (t >= off) ? ssc[t - off] : 0;
    __syncthreads();
    ssc[t] += add;
    __syncthreads();
  }
  int ex = ssc[t] - s;
  loff[i0] = ex;
  loff[i1] = ex + p0;
  if (t == 255) loff[512] = ssc[255];
  __syncthreads();
  int T = ssc[255];
  int slack = (pbase[b + 1] - pb) - T;
  int units = min(slack >> 2, nr);
  if (i0 < nr) row_ptr[r0 + i0] = pb + loff[i0] + 4 * min(i0, units);
  if (i1 < nr) row_ptr[r0 + i1] = pb + loff[i1] + 4 * min(i1, units);
  if (b == NBUCK - 1 && t == 0)
    row_ptr[N_NODES] = pb + loff[nr] + 4 * units;
  __syncthreads();
  for (int i = t; i < ne; i += 256) {
    int2 ed = ebuck[eb + i];
    int lr = ((unsigned)ed.x) >> 17;
    int cl = ed.x & 0x1FFFF;
    int p = loff[lr] + 4 * min(lr, units) + atomicAdd(&lfill[lr], 1);
    epack[pb + p] = make_int2(cl, ed.y);
  }
  __syncthreads();
  for (int i = t; i < nr; i += 256) {
    int a = acnt[i];
    int size_i = ((a + 3) & ~3) + 4 * (i < units);
    int st = loff[i] + 4 * min(i, units);
    for (int p = st + a; p < st + size_i; ++p)
      epack[pb + p] = make_int2(0, 0);
  }
}

// ---------------- propagation, FUSED: all 10 rounds in one cooperative ----
// Grid-stride persistent kernel; body identical to the round-1 spmm (same
// per-row edge order -> bitwise-identical output). grid.sync() between
// rounds; __threadfence() (agent-scope release/acquire: L2 wb+inv) brackets
// the barrier for cross-XCD visibility — same coherence work the 10-dispatch
// version paid at kernel boundaries. Purpose: (a) kill 9 launch gaps + 9
// drain tails (3125 blocks vs 2048 resident = ~35% empty tail/dispatch),
// (b) surface spmm counters as a single top-1 dispatch for the first time.
__global__ __launch_bounds__(256, 4) void spmm_fused_kernel(
    const int* __restrict__ rp, const int2* __restrict__ ep,
    const half_t* __restrict__ x0h, half_t* __restrict__ P,
    half_t* __restrict__ Q, float* __restrict__ fout, int stride)
{
  cg::grid_group grid = cg::this_grid();
  int gt = blockIdx.x * 256 + threadIdx.x;

  for (int i = 0; i < NPROP; ++i) {
    const half_t* xin = (i == 0) ? x0h : ((i & 1) ? P : Q);
    half_t* xout = (i & 1) ? Q : P;
    int last = (i == NPROP - 1);

    for (int u = gt; u < N_NODES * 8; u += stride) {
      int r = u >> 3;
      int c4 = (u & 7) * 4;
      int e0 = rp[r], e1 = rp[r + 1];

      float acc[4] = {0.f, 0.f, 0.f, 0.f};
      for (int e = e0; e < e1; e += 4) {
        int2 p0 = ep[e];
        int2 p1 = ep[e + 1];
        int2 p2 = ep[e + 2];
        int2 p3 = ep[e + 3];
        h4 g0 = *(const h4*)(xin + (size_t)p0.x * D_OUT + c4);
        h4 g1 = *(const h4*)(xin + (size_t)p1.x * D_OUT + c4);
        h4 g2 = *(const h4*)(xin + (size_t)p2.x * D_OUT + c4);
        h4 g3 = *(const h4*)(xin + (size_t)p3.x * D_OUT + c4);
        float v0 = __int_as_float(p0.y);
        float v1 = __int_as_float(p1.y);
        float v2 = __int_as_float(p2.y);
        float v3 = __int_as_float(p3.y);
#pragma unroll
        for (int j = 0; j < 4; ++j) {
          acc[j] = fmaf(v0, (float)g0[j], acc[j]);
          acc[j] = fmaf(v1, (float)g1[j], acc[j]);
          acc[j] = fmaf(v2, (float)g2[j], acc[j]);
          acc[j] = fmaf(v3, (float)g3[j], acc[j]);
        }
      }

      h4 x0v = *(const h4*)(x0h + (size_t)r * D_OUT + c4);
      if (last) {
        float4 o;
        o.x = 0.9f * acc[0] + 0.1f * (float)x0v[0];
        o.y = 0.9f * acc[1] + 0.1f * (float)x0v[1];
        o.z = 0.9f * acc[2] + 0.1f * (float)x0v[2];
        o.w = 0.9f * acc[3] + 0.1f * (float)x0v[3];
        *(float4*)(fout + (size_t)r * D_OUT + c4) = o;
      } else {
        h4 o;
#pragma unroll
        for (int j = 0; j < 4; ++j)
          o[j] = (half_t)(0.9f * acc[j] + 0.1f * (float)x0v[j]);
        *(h4*)(xout + (size_t)r * D_OUT + c4) = o;
      }
    }

    if (!last) {
      __threadfence();   // release: writeback dirty L2 to coherence point
      grid.sync();
      __threadfence();   // acquire: invalidate stale clean L2 lines
    }
  }
}

// ---------------- fallback 10-dispatch spmm (round-1 exact) ----------------
__global__ __launch_bounds__(256) void spmm_kernel(
    const int* __restrict__ rp, const int2* __restrict__ ep,
    const half_t* __restrict__ xin, const half_t* __restrict__ x0h,
    half_t* __restrict__ xout, float* __restrict__ fout, int last)
{
  int gt = blockIdx.x * 256 + threadIdx.x;
  int r = gt >> 3;
  int c4 = (gt & 7) * 4;
  if (r >= N_NODES) return;
  int e0 = rp[r], e1 = rp[r + 1];

  float acc[4] = {0.f, 0.f, 0.f, 0.f};
  for (int e = e0; e < e1; e += 4) {
    int2 p0 = ep[e];
    int2 p1 = ep[e + 1];
    int2 p2 = ep[e + 2];
    int2 p3 = ep[e + 3];
    h4 g0 = *(const h4*)(xin + (size_t)p0.x * D_OUT + c4);
    h4 g1 = *(const h4*)(xin + (size_t)p1.x * D_OUT + c4);
    h4 g2 = *(const h4*)(xin + (size_t)p2.x * D_OUT + c4);
    h4 g3 = *(const h4*)(xin + (size_t)p3.x * D_OUT + c4);
    float v0 = __int_as_float(p0.y);
    float v1 = __int_as_float(p1.y);
    float v2 = __int_as_float(p2.y);
    float v3 = __int_as_float(p3.y);
#pragma unroll
    for (int j = 0; j < 4; ++j) {
      acc[j] = fmaf(v0, (float)g0[j], acc[j]);
      acc[j] = fmaf(v1, (float)g1[j], acc[j]);
      acc[j] = fmaf(v2, (float)g2[j], acc[j]);
      acc[j] = fmaf(v3, (float)g3[j], acc[j]);
    }
  }

  h4 x0v = *(const h4*)(x0h + (size_t)r * D_OUT + c4);
  if (last) {
    float4 o;
    o.x = 0.9f * acc[0] + 0.1f * (float)x0v[0];
    o.y = 0.9f * acc[1] + 0.1f * (float)x0v[1];
    o.z = 0.9f * acc[2] + 0.1f * (float)x0v[2];
    o.w = 0.9f * acc[3] + 0.1f * (float)x0v[3];
    *(float4*)(fout + (size_t)r * D_OUT + c4) = o;
  } else {
    h4 o;
#pragma unroll
    for (int j = 0; j < 4; ++j)
      o[j] = (half_t)(0.9f * acc[j] + 0.1f * (float)x0v[j]);
    *(h4*)(xout + (size_t)r * D_OUT + c4) = o;
  }
}

extern "C" void kernel_launch(void* const* d_in, const int* in_sizes, int n_in,
                              void* d_out, int out_size, void* d_ws, size_t ws_size,
                              hipStream_t stream) {
  const float* F     = (const float*)d_in[0];
  const int*   row   = (const int*)  d_in[1];
  const int*   col   = (const int*)  d_in[2];
  const float* evals = (const float*)d_in[3];
  const float* W1    = (const float*)d_in[4];
  const float* b1    = (const float*)d_in[5];
  const float* W2    = (const float*)d_in[6];
  const float* b2    = (const float*)d_in[7];
  float* out = (float*)d_out;

  // workspace layout (~35.1 MB). ebuck aliases P+Q: ebuck is dead before the
  // first spmm writes P (stream-ordered).
  char* w = (char*)d_ws;
  half_t* x0h    = (half_t*)(w);                //  6,400,000
  half_t* P      = (half_t*)(w +  6400000);     //  6,400,000 (alias ebuck lo)
  half_t* Q      = (half_t*)(w + 12800000);     //  6,400,000 (alias ebuck hi)
  int2*   ebuck  = (int2*)  (w +  6400000);     // 12,800,000
  int2*   epack  = (int2*)  (w + 19200000);     // 15,400,000 (padded CSR)
  int*   row_ptr = (int*)   (w + 34600192);     //    400,128 (N+1)
  int*   bcnt    = (int*)   (w + 35000576);     //      1,024 (zeroed)
  int*   bfill   = (int*)   (w + 35001600);     //      1,024 (zeroed)
  int*   bbase   = (int*)   (w + 35002624);     //      1,024
  int*   pbase   = (int*)   (w + 35003648);     //      1,024
  half_t* W1T    = (half_t*)(w + 35004672);     //     32,768
  half_t* W2T    = (half_t*)(w + 35037440);     //      4,096

  // 1) MLP head -> x0 (fp16)
  pack_kernel<<<64, 256, 0, stream>>>(W1, W2, W1T, W2T);
  mlp_kernel<<<(N_NODES / 16 + 3) / 4, 256, 0, stream>>>(F, W1T, b1, W2T, b2, x0h);

  // 2) CSR build (bucketed two-pass sort, padded rows)
  hipMemsetAsync(bcnt, 0, 2048, stream);   // bcnt + bfill
  bhist_kernel<<<640, 256, 0, stream>>>(row, bcnt);
  bscan_kernel<<<1, 256, 0, stream>>>(bcnt, bbase, pbase);
  bscatter_kernel<<<NCHUNK, 256, 0, stream>>>(row, col, evals, bfill, bbase, ebuck);
  bsort_kernel<<<NBUCK, 256, 0, stream>>>(bbase, pbase, ebuck, epack, row_ptr);

  // 3) propagation: fused cooperative kernel (fallback: 10 dispatches)
  static int g_grid = 0;
  if (g_grid == 0) {
    int nb = 0;
    hipError_t qe = hipOccupancyMaxActiveBlocksPerMultiprocessor(
        &nb, spmm_fused_kernel, 256, 0);
    int cus = 0;
    hipDeviceProp_t prop;
    int dev = 0;
    if (hipGetDevice(&dev) == hipSuccess &&
        hipGetDeviceProperties(&prop, dev) == hipSuccess)
      cus = prop.multiProcessorCount;
    if (qe == hipSuccess && nb > 0 && cus > 0) g_grid = nb * cus;
    if (g_grid <= 0) g_grid = -1;                     // mark: use fallback
    if (g_grid > 3125) g_grid = 3125;                 // >= 1 unit per thread
  }

  bool fused_ok = false;
  if (g_grid > 0) {
    int stride = g_grid * 256;
    const int* rp_p = row_ptr;
    const int2* ep_p = epack;
    const half_t* x0_p = x0h;
    half_t* P_p = P;
    half_t* Q_p = Q;
    float* out_p = out;
    void* args[] = { (void*)&rp_p, (void*)&ep_p, (void*)&x0_p,
                     (void*)&P_p, (void*)&Q_p, (void*)&out_p, (void*)&stride };
    hipError_t le = hipLaunchCooperativeKernel(
        spmm_fused_kernel, dim3(g_grid), dim3(256), args, 0, stream);
    fused_ok = (le == hipSuccess);
    if (!fused_ok) g_grid = -1;   // don't retry on later calls
  }

  if (!fused_ok) {
    const int grid_spmm = (N_NODES * 8 + 255) / 256;
    for (int i = 0; i < NPROP; ++i) {
      const half_t* xin = (i == 0) ? x0h : ((i & 1) ? P : Q);
      half_t* xout = (i & 1) ? Q : P;
      int last = (i == NPROP - 1);
      spmm_kernel<<<grid_spmm, 256, 0, stream>>>(
          row_ptr, epack, xin, x0h, xout, out, last);
    }
  }
}

// Round 8
// 521.126 us; speedup vs baseline: 7.4647x; 7.4647x over previous
//
#include <hip/hip_runtime.h>

#define N_NODES 100000
#define N_EDGES 1600000
#define D_IN    256
#define D_HID   64
#define D_OUT   32
#define NPROP   10

#define NBUCK 196          // bucket = row >> 9 (512 rows/bucket)
#define CHUNK 6080         // edges per bscatter block (LDS-limited)
#define NCHUNK ((N_EDGES + CHUNK - 1) / CHUNK)   // 264

#define MLP_BLOCKS 1563    // ceil(6250 waves / 4)
#define MLP_A 700          // slice sizes: D1 / D2 / D3
#define MLP_B 500
#define MLP_C (MLP_BLOCKS - MLP_A - MLP_B)   // 363

#define SPMM_BLOCKS 2048   // exactly-resident grid; grid-stride over 800000 units

typedef _Float16 half_t;
typedef _Float16 h8  __attribute__((ext_vector_type(8)));
typedef _Float16 h4  __attribute__((ext_vector_type(4)));
typedef float    f4v __attribute__((ext_vector_type(4)));

// ==================== MLP body (round-6 code, as device fn) ====================
#define HSTRIDE 72
#define MLP_LDS_BYTES (4 * 16 * HSTRIDE * 2 + 4 * 16 * 32 * 2)   // 13312

static __device__ __forceinline__ void mlp_body(
    int mb, int t, char* smem,
    const float* __restrict__ F, const half_t* __restrict__ W1T,
    const float* __restrict__ b1, const half_t* __restrict__ W2T,
    const float* __restrict__ b2, half_t* __restrict__ x0h)
{
  half_t* h_lds   = (half_t*)smem;                       // 4*16*72
  half_t* out_lds = (half_t*)(smem + 4 * 16 * HSTRIDE * 2);  // 4*16*32
  int w = t >> 6, lane = t & 63;
  int m = lane & 15, q = lane >> 4;
  int gw = mb * 4 + w;
  int node0 = gw * 16;
  if (node0 > N_NODES - 16) node0 = N_NODES - 16;  // tail waves duplicate last tile

  const float* ap = F + (size_t)(node0 + m) * D_IN + q * 8;
  float4 fr[16];
#pragma unroll
  for (int s = 0; s < 8; ++s) {
    fr[2 * s]     = *(const float4*)(ap + s * 32);
    fr[2 * s + 1] = *(const float4*)(ap + s * 32 + 4);
  }

  h8 af[8];
#pragma unroll
  for (int s = 0; s < 8; ++s) {
    float4 f0 = fr[2 * s], f1 = fr[2 * s + 1];
    h8 a;
    a[0] = (_Float16)f0.x; a[1] = (_Float16)f0.y;
    a[2] = (_Float16)f0.z; a[3] = (_Float16)f0.w;
    a[4] = (_Float16)f1.x; a[5] = (_Float16)f1.y;
    a[6] = (_Float16)f1.z; a[7] = (_Float16)f1.w;
    af[s] = a;
  }

  f4v acc[4];
#pragma unroll
  for (int i = 0; i < 4; ++i) acc[i] = (f4v){0.f, 0.f, 0.f, 0.f};
  const half_t* bp = W1T + (size_t)m * D_IN + q * 8;
#pragma unroll
  for (int s = 0; s < 8; ++s) {
    h8 b0 = *(const h8*)(bp + 0 * 16 * D_IN + s * 32);
    h8 b1v = *(const h8*)(bp + 1 * 16 * D_IN + s * 32);
    h8 b2v = *(const h8*)(bp + 2 * 16 * D_IN + s * 32);
    h8 b3v = *(const h8*)(bp + 3 * 16 * D_IN + s * 32);
    acc[0] = __builtin_amdgcn_mfma_f32_16x16x32_f16(af[s], b0, acc[0], 0, 0, 0);
    acc[1] = __builtin_amdgcn_mfma_f32_16x16x32_f16(af[s], b1v, acc[1], 0, 0, 0);
    acc[2] = __builtin_amdgcn_mfma_f32_16x16x32_f16(af[s], b2v, acc[2], 0, 0, 0);
    acc[3] = __builtin_amdgcn_mfma_f32_16x16x32_f16(af[s], b3v, acc[3], 0, 0, 0);
  }

  half_t* hw = h_lds + w * 16 * HSTRIDE;
#pragma unroll
  for (int ht = 0; ht < 4; ++ht) {
    float bb = b1[ht * 16 + m];
#pragma unroll
    for (int i = 0; i < 4; ++i) {
      float hv = fmaxf(acc[ht][i] + bb, 0.f);
      hw[(q * 4 + i) * HSTRIDE + ht * 16 + m] = (half_t)hv;
    }
  }
  __syncthreads();

  f4v o0 = {0.f, 0.f, 0.f, 0.f}, o1 = {0.f, 0.f, 0.f, 0.f};
#pragma unroll
  for (int s = 0; s < 2; ++s) {
    h8 a = *(const h8*)(hw + m * HSTRIDE + s * 32 + q * 8);
    h8 bb0 = *(const h8*)(W2T + (size_t)m * D_HID + s * 32 + q * 8);
    h8 bb1 = *(const h8*)(W2T + (size_t)(16 + m) * D_HID + s * 32 + q * 8);
    o0 = __builtin_amdgcn_mfma_f32_16x16x32_f16(a, bb0, o0, 0, 0, 0);
    o1 = __builtin_amdgcn_mfma_f32_16x16x32_f16(a, bb1, o1, 0, 0, 0);
  }
  half_t* ow = out_lds + w * 16 * 32;
  {
    float c0 = b2[m], c1 = b2[16 + m];
#pragma unroll
    for (int i = 0; i < 4; ++i) {
      ow[(q * 4 + i) * 32 + m]      = (half_t)(o0[i] + c0);
      ow[(q * 4 + i) * 32 + 16 + m] = (half_t)(o1[i] + c1);
    }
  }
  __syncthreads();

  {
    int nl = lane >> 2, qq = lane & 3;
    *(int4*)(x0h + (size_t)(node0 + nl) * D_OUT + qq * 8) =
        *(const int4*)(ow + nl * 32 + qq * 8);
  }
}

// ==================== D0: bhist (b<640) + weight pack (b>=640) ====================
__global__ __launch_bounds__(256) void mix0_kernel(
    const int* __restrict__ row, int* __restrict__ bcnt,
    const float* __restrict__ W1, const float* __restrict__ W2,
    half_t* __restrict__ W1T, half_t* __restrict__ W2T)
{
  __shared__ int lb[NBUCK];
  int b = blockIdx.x, t = threadIdx.x;
  if (b < 640) {
    for (int i = t; i < NBUCK; i += 256) lb[i] = 0;
    __syncthreads();
    const int stride = 640 * 256;
    for (int e = b * 256 + t; e < N_EDGES; e += stride)
      atomicAdd(&lb[row[e] >> 9], 1);
    __syncthreads();
    for (int i = t; i < NBUCK; i += 256)
      if (lb[i]) atomicAdd(&bcnt[i], lb[i]);
  } else {
    int g = (b - 640) * 256 + t;
    if (g < 64 * 256) { int n = g >> 8, k = g & 255; W1T[g] = (half_t)W1[k * 64 + n]; }
    if (g < 32 * 64)  { int n = g >> 6, k = g & 63;  W2T[g] = (half_t)W2[k * 32 + n]; }
  }
}

// ==================== D1: bscan (b==0) + mlp slice A ====================
__global__ __launch_bounds__(256, 2) void mix1_kernel(
    const int* __restrict__ bcnt, int* __restrict__ bbase, int* __restrict__ pbase,
    const float* __restrict__ F, const half_t* __restrict__ W1T,
    const float* __restrict__ b1, const half_t* __restrict__ W2T,
    const float* __restrict__ b2, half_t* __restrict__ x0h)
{
  __shared__ __align__(16) char smem[MLP_LDS_BYTES];   // mlp needs 13312; bscan 2KB
  int b = blockIdx.x, t = threadIdx.x;
  if (b == 0) {
    int* l1 = (int*)smem;           // 256 ints
    int* l2 = (int*)smem + 256;     // 256 ints
    int a = (t < NBUCK) ? bcnt[t] : 0;
    int r = (t < NBUCK) ? (((a + 3) & ~3) + 3 * 512) : 0;
    l1[t] = a; l2[t] = r;
    __syncthreads();
    for (int off = 1; off < 256; off <<= 1) {
      int x1 = (t >= off) ? l1[t - off] : 0;
      int x2 = (t >= off) ? l2[t - off] : 0;
      __syncthreads();
      l1[t] += x1; l2[t] += x2;
      __syncthreads();
    }
    if (t < NBUCK) { bbase[t] = l1[t] - a; pbase[t] = l2[t] - r; }
    if (t == NBUCK - 1) { bbase[NBUCK] = l1[t]; pbase[NBUCK] = l2[t]; }
  } else {
    mlp_body(b - 1, t, smem, F, W1T, b1, W2T, b2, x0h);
  }
}

// ==================== D2: bscatter (b<264) + mlp slice B ====================
__global__ __launch_bounds__(256, 2) void mix2_kernel(
    const int* __restrict__ row, const int* __restrict__ col,
    const float* __restrict__ vals, int* __restrict__ bfill,
    const int* __restrict__ bbase, int2* __restrict__ ebuck,
    const float* __restrict__ F, const half_t* __restrict__ W1T,
    const float* __restrict__ b1, const half_t* __restrict__ W2T,
    const float* __restrict__ b2, half_t* __restrict__ x0h)
{
  // bscatter LDS (sum with mlp's: 64,960 + 13,312 = 78,272 B -> 2 blocks/CU,
  // same residency both branches had before)
  __shared__ int2 img[CHUNK];
  __shared__ unsigned short sbk[CHUNK];
  __shared__ int cnt[NBUCK], base[NBUCK], gb[NBUCK], fil[NBUCK];
  __shared__ int ssc[256];
  __shared__ __align__(16) char smem[MLP_LDS_BYTES];
  int b = blockIdx.x, t = threadIdx.x;

  if (b < NCHUNK) {
    int e0 = b * CHUNK;
    int n = min(CHUNK, N_EDGES - e0);

    for (int i = t; i < NBUCK; i += 256) { cnt[i] = 0; fil[i] = 0; }
    __syncthreads();
    for (int i = t; i < n; i += 256) atomicAdd(&cnt[row[e0 + i] >> 9], 1);
    __syncthreads();
    int c = (t < NBUCK) ? cnt[t] : 0;
    ssc[t] = c;
    __syncthreads();
    for (int off = 1; off < 256; off <<= 1) {
      int add = (t >= off) ? ssc[t - off] : 0;
      __syncthreads();
      ssc[t] += add;
      __syncthreads();
    }
    if (t < NBUCK) {
      base[t] = ssc[t] - c;
      gb[t] = c ? atomicAdd(&bfill[t], c) : 0;
    }
    __syncthreads();
    for (int i = t; i < n; i += 256) {
      int r = row[e0 + i];
      int bk = r >> 9;
      int p = base[bk] + atomicAdd(&fil[bk], 1);
      img[p] = make_int2(col[e0 + i] | ((r & 511) << 17),
                         __float_as_int(vals[e0 + i]));
      sbk[p] = (unsigned short)bk;
    }
    __syncthreads();
    for (int i = t; i < n; i += 256) {
      int bk = sbk[i];
      ebuck[bbase[bk] + gb[bk] + (i - base[bk])] = img[i];
    }
  } else {
    mlp_body(MLP_A + (b - NCHUNK), t, smem, F, W1T, b1, W2T, b2, x0h);
  }
}

// ==================== D3: bsort (b<196) + mlp slice C ====================
__global__ __launch_bounds__(256, 2) void mix3_kernel(
    const int* __restrict__ bbase, const int* __restrict__ pbase,
    const int2* __restrict__ ebuck, int2* __restrict__ epack,
    int* __restrict__ row_ptr,
    const float* __restrict__ F, const half_t* __restrict__ W1T,
    const float* __restrict__ b1, const half_t* __restrict__ W2T,
    const float* __restrict__ b2, half_t* __restrict__ x0h)
{
  __shared__ int acnt[512], loff[513], lfill[512], ssc[256];
  __shared__ __align__(16) char smem[MLP_LDS_BYTES];
  int b = blockIdx.x, t = threadIdx.x;

  if (b < NBUCK) {
    int r0 = b * 512;
    int nr = min(512, N_NODES - r0);
    int eb = bbase[b];
    int ne = bbase[b + 1] - eb;
    int pb = pbase[b];

    acnt[t] = 0; acnt[t + 256] = 0;
    lfill[t] = 0; lfill[t + 256] = 0;
    __syncthreads();
    for (int i = t; i < ne; i += 256)
      atomicAdd(&acnt[((unsigned)ebuck[eb + i].x) >> 17], 1);
    __syncthreads();
    int i0 = 2 * t, i1 = 2 * t + 1;
    int a0 = acnt[i0], a1 = acnt[i1];
    int p0 = (a0 + 3) & ~3, p1 = (a1 + 3) & ~3;
    int s = p0 + p1;
    ssc[t] = s;
    __syncthreads();
    for (int off = 1; off < 256; off <<= 1) {
      int add = (t >= off) ? ssc[t - off] : 0;
      __syncthreads();
      ssc[t] += add;
      __syncthreads();
    }
    int ex = ssc[t] - s;
    loff[i0] = ex;
    loff[i1] = ex + p0;
    if (t == 255) loff[512] = ssc[255];
    __syncthreads();
    int T = ssc[255];
    int slack = (pbase[b + 1] - pb) - T;
    int units = min(slack >> 2, nr);
    if (i0 < nr) row_ptr[r0 + i0] = pb + loff[i0] + 4 * min(i0, units);
    if (i1 < nr) row_ptr[r0 + i1] = pb + loff[i1] + 4 * min(i1, units);
    if (b == NBUCK - 1 && t == 0)
      row_ptr[N_NODES] = pb + loff[nr] + 4 * units;
    __syncthreads();
    for (int i = t; i < ne; i += 256) {
      int2 ed = ebuck[eb + i];
      int lr = ((unsigned)ed.x) >> 17;
      int cl = ed.x & 0x1FFFF;
      int p = loff[lr] + 4 * min(lr, units) + atomicAdd(&lfill[lr], 1);
      epack[pb + p] = make_int2(cl, ed.y);
    }
    __syncthreads();
    for (int i = t; i < nr; i += 256) {
      int a = acnt[i];
      int size_i = ((a + 3) & ~3) + 4 * (i < units);
      int st = loff[i] + 4 * min(i, units);
      for (int p = st + a; p < st + size_i; ++p)
        epack[pb + p] = make_int2(0, 0);
    }
  } else {
    mlp_body(MLP_A + MLP_B + (b - NBUCK), t, smem, F, W1T, b1, W2T, b2, x0h);
  }
}

// ==================== propagation (round-1 body, exactly-resident grid) ====
// Grid-stride over SPMM_BLOCKS=2048 blocks (1-2 units/thread) flattens the
// 3125-block two-generation schedule into ~1.5 -> no low-occupancy drain
// tail. Same unit->row/channel mapping, same edge order -> bitwise output.
__global__ __launch_bounds__(256) void spmm_kernel(
    const int* __restrict__ rp, const int2* __restrict__ ep,
    const half_t* __restrict__ xin, const half_t* __restrict__ x0h,
    half_t* __restrict__ xout, float* __restrict__ fout, int last)
{
  int gt = blockIdx.x * 256 + threadIdx.x;
  const int stride = SPMM_BLOCKS * 256;
  for (int u = gt; u < N_NODES * 8; u += stride) {
    int r = u >> 3;
    int c4 = (u & 7) * 4;
    int e0 = rp[r], e1 = rp[r + 1];

    float acc[4] = {0.f, 0.f, 0.f, 0.f};
    for (int e = e0; e < e1; e += 4) {
      int2 p0 = ep[e];
      int2 p1 = ep[e + 1];
      int2 p2 = ep[e + 2];
      int2 p3 = ep[e + 3];
      h4 g0 = *(const h4*)(xin + (size_t)p0.x * D_OUT + c4);
      h4 g1 = *(const h4*)(xin + (size_t)p1.x * D_OUT + c4);
      h4 g2 = *(const h4*)(xin + (size_t)p2.x * D_OUT + c4);
      h4 g3 = *(const h4*)(xin + (size_t)p3.x * D_OUT + c4);
      float v0 = __int_as_float(p0.y);
      float v1 = __int_as_float(p1.y);
      float v2 = __int_as_float(p2.y);
      float v3 = __int_as_float(p3.y);
#pragma unroll
      for (int j = 0; j < 4; ++j) {
        acc[j] = fmaf(v0, (float)g0[j], acc[j]);
        acc[j] = fmaf(v1, (float)g1[j], acc[j]);
        acc[j] = fmaf(v2, (float)g2[j], acc[j]);
        acc[j] = fmaf(v3, (float)g3[j], acc[j]);
      }
    }

    h4 x0v = *(const h4*)(x0h + (size_t)r * D_OUT + c4);
    if (last) {
      float4 o;
      o.x = 0.9f * acc[0] + 0.1f * (float)x0v[0];
      o.y = 0.9f * acc[1] + 0.1f * (float)x0v[1];
      o.z = 0.9f * acc[2] + 0.1f * (float)x0v[2];
      o.w = 0.9f * acc[3] + 0.1f * (float)x0v[3];
      *(float4*)(fout + (size_t)r * D_OUT + c4) = o;
    } else {
      h4 o;
#pragma unroll
      for (int j = 0; j < 4; ++j)
        o[j] = (half_t)(0.9f * acc[j] + 0.1f * (float)x0v[j]);
      *(h4*)(xout + (size_t)r * D_OUT + c4) = o;
    }
  }
}

extern "C" void kernel_launch(void* const* d_in, const int* in_sizes, int n_in,
                              void* d_out, int out_size, void* d_ws, size_t ws_size,
                              hipStream_t stream) {
  const float* F     = (const float*)d_in[0];
  const int*   row   = (const int*)  d_in[1];
  const int*   col   = (const int*)  d_in[2];
  const float* evals = (const float*)d_in[3];
  const float* W1    = (const float*)d_in[4];
  const float* b1    = (const float*)d_in[5];
  const float* W2    = (const float*)d_in[6];
  const float* b2    = (const float*)d_in[7];
  float* out = (float*)d_out;

  // workspace layout (~35.1 MB). ebuck aliases P+Q: ebuck is dead before the
  // first spmm writes P (stream-ordered).
  char* w = (char*)d_ws;
  half_t* x0h    = (half_t*)(w);                //  6,400,000
  half_t* P      = (half_t*)(w +  6400000);     //  6,400,000 (alias ebuck lo)
  half_t* Q      = (half_t*)(w + 12800000);     //  6,400,000 (alias ebuck hi)
  int2*   ebuck  = (int2*)  (w +  6400000);     // 12,800,000
  int2*   epack  = (int2*)  (w + 19200000);     // 15,400,000 (padded CSR)
  int*   row_ptr = (int*)   (w + 34600192);     //    400,128 (N+1)
  int*   bcnt    = (int*)   (w + 35000576);     //      1,024 (zeroed)
  int*   bfill   = (int*)   (w + 35001600);     //      1,024 (zeroed)
  int*   bbase   = (int*)   (w + 35002624);     //      1,024
  int*   pbase   = (int*)   (w + 35003648);     //      1,024
  half_t* W1T    = (half_t*)(w + 35004672);     //     32,768
  half_t* W2T    = (half_t*)(w + 35037440);     //      4,096

  // D0: bhist + weight pack (independent)
  hipMemsetAsync(bcnt, 0, 2048, stream);   // bcnt + bfill
  mix0_kernel<<<640 + 64, 256, 0, stream>>>(row, bcnt, W1, W2, W1T, W2T);

  // D1-D3: CSR chain, each overlapped with an MLP slice (mlp needs W1T: D0 done)
  mix1_kernel<<<1 + MLP_A, 256, 0, stream>>>(
      bcnt, bbase, pbase, F, W1T, b1, W2T, b2, x0h);
  mix2_kernel<<<NCHUNK + MLP_B, 256, 0, stream>>>(
      row, col, evals, bfill, bbase, ebuck, F, W1T, b1, W2T, b2, x0h);
  mix3_kernel<<<NBUCK + MLP_C, 256, 0, stream>>>(
      bbase, pbase, ebuck, epack, row_ptr, F, W1T, b1, W2T, b2, x0h);

  // 10 propagation rounds: x0h -> P -> Q -> ... final writes fp32 d_out
  for (int i = 0; i < NPROP; ++i) {
    const half_t* xin = (i == 0) ? x0h : ((i & 1) ? P : Q);
    half_t* xout = (i & 1) ? Q : P;
    int last = (i == NPROP - 1);
    spmm_kernel<<<SPMM_BLOCKS, 256, 0, stream>>>(
        row_ptr, epack, xin, x0h, xout, out, last);
  }
}